// Round 1
// baseline (603.151 us; speedup 1.0000x reference)
//
#include <hip/hip_runtime.h>

// Problem shape (fixed by setup_inputs):
//   x: [B=32, S=2048, F=128] fp32, window W=16
//   out: [B, S, W, F] fp32, out[b,i,w,f] = (i+w < S) ? x[b,i+w,f] : 0
//
// Key observation: for fixed (b,i), out[b,i,:,:] flattened (W*F = 2048 floats)
// is a CONTIGUOUS copy of x starting at flat offset b*S*F + i*F, with zeros
// for any element whose source row i + w >= S. Pure streaming copy.

#define B_ 32
#define S_ 2048
#define F_ 128
#define W_ 16

__global__ __launch_bounds__(256) void WindowingLayer_22084721836441_kernel(
    const float4* __restrict__ x, float4* __restrict__ out, long long total4) {
    // Units: float4 (16 B). Per-(b,i) chunk = W*F/4 = 512 float4s.
    // o -> chunk = o>>9, r = o&511
    // chunk -> b = chunk>>11 (S=2048), i = chunk&2047
    // source row = i + r/(F/4) = i + (r>>5); src float4 = b*S*32 + i*32 + r
    long long idx = (long long)blockIdx.x * blockDim.x + threadIdx.x;
    long long stride = (long long)gridDim.x * blockDim.x;
    for (long long o = idx; o < total4; o += stride) {
        long long chunk = o >> 9;
        int r = (int)(o & 511);
        int b = (int)(chunk >> 11);
        int i = (int)(chunk & (S_ - 1));
        int row = i + (r >> 5);
        float4 v = make_float4(0.f, 0.f, 0.f, 0.f);
        if (row < S_) {
            v = x[(long long)b * (S_ * (F_ / 4)) + (long long)i * (F_ / 4) + r];
        }
        out[o] = v;
    }
}

extern "C" void kernel_launch(void* const* d_in, const int* in_sizes, int n_in,
                              void* d_out, int out_size, void* d_ws, size_t ws_size,
                              hipStream_t stream) {
    const float4* x = (const float4*)d_in[0];
    float4* out = (float4*)d_out;
    long long total4 = (long long)B_ * S_ * W_ * F_ / 4;  // 33,554,432
    int block = 256;
    int grid = 2048;  // grid-stride; 8192 waves over 256 CUs
    WindowingLayer_22084721836441_kernel<<<grid, block, 0, stream>>>(x, out, total4);
}

// Round 5
// 593.927 us; speedup vs baseline: 1.0155x; 1.0155x over previous
//
#include <hip/hip_runtime.h>

// Problem shape (fixed by setup_inputs):
//   x: [B=32, S=2048, F=128] fp32, window W=16
//   out: [B, S, W, F] fp32, out[b,i,w,f] = (i+w < S) ? x[b,i+w,f] : 0
//
// out[b,i,:,:] flattened (W*F = 2048 floats = 512 float4) is a CONTIGUOUS
// copy of x starting at flat float4 index (b*2048+i)*32, zero past row S.
// In float4 units with o = output index:
//   chunk = o>>9  ( = b*2048 + i exactly )
//   r     = o&511
//   src   = (chunk<<5) + r      valid iff (chunk&2047) + (r>>5) < 2048
//
// Pure streaming: 537 MB stores + ~34 MB HBM reads (x is 32 MiB, L3-resident
// across its 16x reuse). Floor ~95 us at 6.3 TB/s.
//
// This version: 4x-unrolled grid-stride (4 independent loads in flight per
// wave before the stores), lane-contiguous so every load/store is a fully
// coalesced 1 KB/wave instruction.

#define TOTAL4 33554432LL   // 32*2048*16*128/4
#define NBLK   4096
#define NTHR   256
#define STRIDE (NBLK * NTHR)          // 1,048,576 float4 per sweep
#define NITER  (TOTAL4 / STRIDE)      // 32 sweeps per thread
#define UNROLL 4

__global__ __launch_bounds__(NTHR) void WindowingLayer_22084721836441_kernel(
    const float4* __restrict__ x, float4* __restrict__ out) {
    long long base = (long long)blockIdx.x * NTHR + threadIdx.x;
#pragma unroll 1
    for (int t = 0; t < NITER / UNROLL; ++t) {
        long long o[UNROLL];
        float4 v[UNROLL];
#pragma unroll
        for (int k = 0; k < UNROLL; ++k) {
            o[k] = base + (long long)(t * UNROLL + k) * STRIDE;
            long long chunk = o[k] >> 9;          // b*2048 + i
            int r = (int)(o[k] & 511);
            int row = (int)(chunk & 2047) + (r >> 5);
            v[k] = make_float4(0.f, 0.f, 0.f, 0.f);
            if (row < 2048) {
                v[k] = x[(chunk << 5) + r];
            }
        }
#pragma unroll
        for (int k = 0; k < UNROLL; ++k) {
            out[o[k]] = v[k];
        }
    }
}

extern "C" void kernel_launch(void* const* d_in, const int* in_sizes, int n_in,
                              void* d_out, int out_size, void* d_ws, size_t ws_size,
                              hipStream_t stream) {
    const float4* x = (const float4*)d_in[0];
    float4* out = (float4*)d_out;
    WindowingLayer_22084721836441_kernel<<<NBLK, NTHR, 0, stream>>>(x, out);
}